// Round 1
// baseline (230.811 us; speedup 1.0000x reference)
//
#include <hip/hip_runtime.h>

// Sparsemax over last dim d=1024, rows = 8*4096 = 32768, fp32.
// One wave (64 lanes) per row; 16 elements per lane held in registers.
// tau found by 20-step bisection on [max-1, max] + exact Newton polish.

#define ROW_D 1024

__device__ __forceinline__ float wave_allreduce_sum(float v) {
#pragma unroll
    for (int off = 1; off < 64; off <<= 1)
        v += __shfl_xor(v, off, 64);
    return v;
}

__device__ __forceinline__ float wave_allreduce_max(float v) {
#pragma unroll
    for (int off = 1; off < 64; off <<= 1)
        v = fmaxf(v, __shfl_xor(v, off, 64));
    return v;
}

__global__ __launch_bounds__(256) void sparsemax_kernel(
    const float* __restrict__ z, float* __restrict__ out, int nrows) {
    const int gwave = (int)((blockIdx.x * 256u + threadIdx.x) >> 6);
    const int lane  = (int)(threadIdx.x & 63u);
    if (gwave >= nrows) return;

    const float4* __restrict__ zin  =
        reinterpret_cast<const float4*>(z + (size_t)gwave * ROW_D);
    float4* __restrict__ pout =
        reinterpret_cast<float4*>(out + (size_t)gwave * ROW_D);

    // Load 16 elements (4x float4), coalesced: lane i reads vec idx i, i+64, ...
    float4 v[4];
#pragma unroll
    for (int j = 0; j < 4; ++j) v[j] = zin[lane + 64 * j];

    // Row max
    float m = fmaxf(fmaxf(v[0].x, v[0].y), fmaxf(v[0].z, v[0].w));
#pragma unroll
    for (int j = 1; j < 4; ++j)
        m = fmaxf(m, fmaxf(fmaxf(v[j].x, v[j].y), fmaxf(v[j].z, v[j].w)));
    m = wave_allreduce_max(m);

    // Bisection: invariant f(lo) >= 0, f(hi) < 0, where f(t)=sum(relu(z-t))-1
    float lo = m - 1.0f, hi = m;
#pragma unroll
    for (int it = 0; it < 20; ++it) {
        const float tau = 0.5f * (lo + hi);
        float s = 0.0f;
#pragma unroll
        for (int j = 0; j < 4; ++j) {
            s += fmaxf(v[j].x - tau, 0.0f);
            s += fmaxf(v[j].y - tau, 0.0f);
            s += fmaxf(v[j].z - tau, 0.0f);
            s += fmaxf(v[j].w - tau, 0.0f);
        }
        s = wave_allreduce_sum(s);
        // s is wave-uniform -> no divergence
        if (s >= 1.0f) lo = tau; else hi = tau;
    }

    // Newton polish: exact root of the linear segment containing lo.
    // Support set {z > lo} has k>=1 (max element always qualifies: lo < m).
    float s = 0.0f, k = 0.0f;
#pragma unroll
    for (int j = 0; j < 4; ++j) {
        float e;
        e = v[j].x; if (e > lo) { s += e; k += 1.0f; }
        e = v[j].y; if (e > lo) { s += e; k += 1.0f; }
        e = v[j].z; if (e > lo) { s += e; k += 1.0f; }
        e = v[j].w; if (e > lo) { s += e; k += 1.0f; }
    }
    s = wave_allreduce_sum(s);
    k = wave_allreduce_sum(k);
    float tau = (s - 1.0f) / k;
    tau = fminf(fmaxf(tau, lo), hi);  // clamp: exact unless a breakpoint sits in (lo,hi)

    // p = relu(z - tau), coalesced float4 stores
#pragma unroll
    for (int j = 0; j < 4; ++j) {
        float4 o;
        o.x = fmaxf(v[j].x - tau, 0.0f);
        o.y = fmaxf(v[j].y - tau, 0.0f);
        o.z = fmaxf(v[j].z - tau, 0.0f);
        o.w = fmaxf(v[j].w - tau, 0.0f);
        pout[lane + 64 * j] = o;
    }
}

extern "C" void kernel_launch(void* const* d_in, const int* in_sizes, int n_in,
                              void* d_out, int out_size, void* d_ws, size_t ws_size,
                              hipStream_t stream) {
    const float* z = (const float*)d_in[0];
    float* out = (float*)d_out;
    const int n = in_sizes[0];          // 8*4096*1024
    const int nrows = n / ROW_D;        // 32768
    // 4 waves (rows) per 256-thread block
    const int blocks = (nrows + 3) / 4;
    sparsemax_kernel<<<blocks, 256, 0, stream>>>(z, out, nrows);
}

// Round 2
// 230.017 us; speedup vs baseline: 1.0035x; 1.0035x over previous
//
#include <hip/hip_runtime.h>

// Sparsemax, last dim d=1024, 32768 rows, fp32. One wave per row.
//
// Structure exploited: tau* in [max-1, max), so only elements z > max-1
// (typically ~14 of 1024 for Gaussian rows) affect the root of
// f(t) = sum(relu(z-t)) - 1. Compact those candidates into LDS via
// ballot-prefix, bisect on <=2 candidates/lane, exact Newton polish.

#define ROW_D 1024
#define CAP   128      // fast-path capacity for candidates per row
#define NEG_PAD -3.0e38f

__device__ __forceinline__ float wsum(float v) {
#pragma unroll
    for (int off = 1; off < 64; off <<= 1) v += __shfl_xor(v, off, 64);
    return v;
}
__device__ __forceinline__ float wmax(float v) {
#pragma unroll
    for (int off = 1; off < 64; off <<= 1) v = fmaxf(v, __shfl_xor(v, off, 64));
    return v;
}

__global__ __launch_bounds__(256) void sparsemax_kernel(
    const float* __restrict__ z, float* __restrict__ out, int nrows) {
    const int wslot = (int)(threadIdx.x >> 6);
    const int lane  = (int)(threadIdx.x & 63u);
    int row = (int)(blockIdx.x << 2) + wslot;
    if (row >= nrows) row = nrows - 1;   // grid is exact; never taken, keeps barrier safe

    __shared__ float cbuf[4][CAP];

    const float4* __restrict__ zin =
        reinterpret_cast<const float4*>(z + (size_t)row * ROW_D);
    float4* __restrict__ pout =
        reinterpret_cast<float4*>(out + (size_t)row * ROW_D);

    // Load 16 elements/lane, coalesced.
    float4 v[4];
#pragma unroll
    for (int j = 0; j < 4; ++j) v[j] = zin[lane + 64 * j];

    // Row max.
    float m = fmaxf(fmaxf(v[0].x, v[0].y), fmaxf(v[0].z, v[0].w));
#pragma unroll
    for (int j = 1; j < 4; ++j)
        m = fmaxf(m, fmaxf(fmaxf(v[j].x, v[j].y), fmaxf(v[j].z, v[j].w)));
    m = wmax(m);
    const float lo0 = m - 1.0f;   // f(lo0) >= 0, f(m) = -1 < 0

    // Pad slots, then ballot-prefix compaction of candidates (z > lo0).
    cbuf[wslot][lane]      = NEG_PAD;
    cbuf[wslot][lane + 64] = NEG_PAD;
    const unsigned long long ltmask = (1ULL << lane) - 1ULL;
    int base = 0;
#pragma unroll
    for (int j = 0; j < 4; ++j) {
        const float e[4] = {v[j].x, v[j].y, v[j].z, v[j].w};
#pragma unroll
        for (int c = 0; c < 4; ++c) {
            const bool cand = e[c] > lo0;
            const unsigned long long b = __ballot(cand);
            const int pos = base + __popcll(b & ltmask);
            if (cand && pos < CAP) cbuf[wslot][pos] = e[c];
            base += __popcll(b);
        }
    }
    __syncthreads();   // insurance for LDS write->read ordering
    const int K = base;

    float tau;
    if (K <= CAP) {
        // Fast path: bisect on <=2 candidate values per lane.
        const float x0 = cbuf[wslot][lane];
        const float x1 = cbuf[wslot][lane + 64];
        float lo = lo0, hi = m;
#pragma unroll
        for (int it = 0; it < 12; ++it) {
            const float t = 0.5f * (lo + hi);
            float s = fmaxf(x0 - t, 0.0f) + fmaxf(x1 - t, 0.0f);
            s = wsum(s);
            if (s >= 1.0f) lo = t; else hi = t;   // s wave-uniform
        }
        float s = 0.0f, k = 0.0f;
        if (x0 > lo) { s += x0; k += 1.0f; }
        if (x1 > lo) { s += x1; k += 1.0f; }
        s = wsum(s); k = wsum(k);
        tau = fminf(fmaxf((s - 1.0f) / k, lo), hi);
    } else {
        // Robust fallback (never expected on this data): full-row bisection.
        float lo = lo0, hi = m;
        for (int it = 0; it < 24; ++it) {
            const float t = 0.5f * (lo + hi);
            float s = 0.0f;
#pragma unroll
            for (int j = 0; j < 4; ++j) {
                s += fmaxf(v[j].x - t, 0.0f);
                s += fmaxf(v[j].y - t, 0.0f);
                s += fmaxf(v[j].z - t, 0.0f);
                s += fmaxf(v[j].w - t, 0.0f);
            }
            s = wsum(s);
            if (s >= 1.0f) lo = t; else hi = t;
        }
        float s = 0.0f, k = 0.0f;
#pragma unroll
        for (int j = 0; j < 4; ++j) {
            float e;
            e = v[j].x; if (e > lo) { s += e; k += 1.0f; }
            e = v[j].y; if (e > lo) { s += e; k += 1.0f; }
            e = v[j].z; if (e > lo) { s += e; k += 1.0f; }
            e = v[j].w; if (e > lo) { s += e; k += 1.0f; }
        }
        s = wsum(s); k = wsum(k);
        tau = fminf(fmaxf((s - 1.0f) / k, lo), hi);
    }

    // p = relu(z - tau), coalesced float4 stores.
#pragma unroll
    for (int j = 0; j < 4; ++j) {
        float4 o;
        o.x = fmaxf(v[j].x - tau, 0.0f);
        o.y = fmaxf(v[j].y - tau, 0.0f);
        o.z = fmaxf(v[j].z - tau, 0.0f);
        o.w = fmaxf(v[j].w - tau, 0.0f);
        pout[lane + 64 * j] = o;
    }
}

extern "C" void kernel_launch(void* const* d_in, const int* in_sizes, int n_in,
                              void* d_out, int out_size, void* d_ws, size_t ws_size,
                              hipStream_t stream) {
    const float* z = (const float*)d_in[0];
    float* out = (float*)d_out;
    const int n = in_sizes[0];       // 8*4096*1024
    const int nrows = n / ROW_D;     // 32768
    const int blocks = (nrows + 3) / 4;   // 4 rows (waves) per block
    sparsemax_kernel<<<blocks, 256, 0, stream>>>(z, out, nrows);
}